// Round 10
// baseline (1250.650 us; speedup 1.0000x reference)
//
#include <hip/hip_runtime.h>

// NetG: seq2seq GRU (enc GRU -> +noise -> dec GRU -> FC head)
// B=512, T=256, H=256, D=3.
//
// R21 = R20 with the REAL spill cause fixed + a reg-diet insurance trim.
//   R20 post-mortem: VGPR=128 + 151MB spill traffic despite a "2/SIMD"
//   launch_bounds. Cross-round evidence ((512,2)->cap 128 in R12/R20;
//   (1024,4)->cap 64 in R16/R17/R19) shows this toolchain treats the 2nd
//   __launch_bounds__ arg as CUDA-style MIN BLOCKS PER CU: (512,2) = 16
//   waves/CU = 4/SIMD = 128-reg cap. Fix: __launch_bounds__(512, 1) ->
//   8 waves/CU = 2/SIMD = 256-reg budget (either arg semantics gives
//   >=256 here).
//   Insurance trim (261 -> ~240 regs): n-gate x contribution computed
//   SCALARLY in the value-lane epilogue (nx = sum_j Wihn[d,j]*x[cv,j,t]
//   + bihn[d]; 3 resident f32 weights per value + one b64 shX read per
//   lane-step). Deletes acc3 (8 regs), ax[.][2] (4 regs), and 6 of 54
//   MFMAs/step. f32-weighted nx >= old bf16 precision.
// Structure (R20): 128 blocks x 512 thr (8 waves, 2 tiles/wave, 2/SIMD),
// NB=4 real batches/block. Wf[2][3][8]=192 regs: ALL W_hh resident -
// zero weight traffic. Compact h [2 parity][1024] (predicated 256B bf
// reads, shared across both tiles of the wave), compact x, swizzled
// wave-private scatter/gather epilogue (R19-verified, 0 conflicts):
// GEMM lanes c<4 scatter {r,z,nh}; every lane finalizes 2 values
// (12 trans). fp32 value-lane h carry (exact). One barrier/step.

#define B_TOT 512
#define T_LEN 256
#define HID 256
#define NBATCH 16              // MFMA column count (cols >= NB are pad)
#define NB 4                   // real batches per block
#define NTHREADS 512           // 8 waves, 2 tiles/wave
#define NBLK (B_TOT / NB)      // 128

#define XSLOTS (T_LEN + 1)
#define XT 16                  // compact x slot: 4 cols x 4 shorts
#define HBUF (NB * HID)        // 1024 shorts per h parity buffer

// LDS partition (units: shorts)
#define H_OFF 0                          // 2 x 1024
#define X_OFF (2 * HBUF)                 // 2048
#define RD_OFF (X_OFF + XSLOTS * XT)     // 2048 + 4112 = 6160
#define SMEM_SHORTS (RD_OFF + 8 * 1024)  // + 8 waves x 2KB scratch = 14352
#define SMEM_BYTES  (SMEM_SHORTS * 2)    // 28704 B

typedef __attribute__((ext_vector_type(4))) float f32x4;
typedef __attribute__((ext_vector_type(8))) short shortx8;
typedef __attribute__((ext_vector_type(4))) short i16x4;
typedef __attribute__((ext_vector_type(4))) unsigned short ushortx4;
typedef __attribute__((ext_vector_type(8))) unsigned short ushortx8;

#if __has_builtin(__builtin_amdgcn_mfma_f32_16x16x16_bf16)
#define HAVE_K16 1
#define MFMA_X(A, B, C) __builtin_amdgcn_mfma_f32_16x16x16_bf16((A), (B), (C), 0, 0, 0)
#elif __has_builtin(__builtin_amdgcn_mfma_f32_16x16x16bf16_1k)
#define HAVE_K16 1
#define MFMA_X(A, B, C) __builtin_amdgcn_mfma_f32_16x16x16bf16_1k((A), (B), (C), 0, 0, 0)
#else
#define HAVE_K16 0
#endif

__device__ __forceinline__ unsigned short f2bf(float x) {
    unsigned u = __float_as_uint(x);
    u += 0x7FFF + ((u >> 16) & 1);   // RNE
    return (unsigned short)(u >> 16);
}
__device__ __forceinline__ float bf2f(unsigned short s) {
    return __uint_as_float(((unsigned)s) << 16);
}
__device__ __forceinline__ float fastrcp(float x) {
#if __has_builtin(__builtin_amdgcn_rcpf)
    return __builtin_amdgcn_rcpf(x);
#else
    return 1.0f / x;
#endif
}
__device__ __forceinline__ float exp2raw(float y) {
#if __has_builtin(__builtin_amdgcn_exp2f)
    return __builtin_amdgcn_exp2f(y);
#else
    return __expf(y * 0.69314718056f);
#endif
}
__device__ __forceinline__ float sigmoid_(float x) {
    return fastrcp(1.0f + exp2raw(x * -1.44269504f));
}
__device__ __forceinline__ float tanh_(float x) {
    return 2.0f * fastrcp(1.0f + exp2raw(x * -2.88539008f)) - 1.0f;
}

template<int IS_DEC>
__global__ __launch_bounds__(NTHREADS, 1) void gru_persistent(
    const float* __restrict__ X,       // [512][256][3]
    const float* __restrict__ W_hh,    // [768][256] gates r,z,n
    const float* __restrict__ W_ih,    // [768][3]
    const float* __restrict__ b_ih,    // [768]
    const float* __restrict__ b_hh,    // [768]
    const float* __restrict__ h_in,    // dec: [512][256] fp32; enc: null
    const float* __restrict__ noise,   // dec: [512][256]; enc: null
    float* __restrict__ h_out,         // enc: [512][256] fp32; dec: null
    unsigned short* __restrict__ Yout) // dec: [128][256][4][256] bf16
{
    extern __shared__ unsigned short smem[];
    unsigned short* shH  = smem + H_OFF;   // 2 compact parity buffers
    unsigned short* shX  = smem + X_OFF;
    unsigned short* shRd = smem + RD_OFF;

    const int tid  = threadIdx.x;
    const int g    = blockIdx.x;
    const int w    = tid >> 6;        // wave 0..7; owns tiles {w, w+8}
    const int lane = tid & 63;
    const int c    = lane & 15;       // GEMM: A-row within tile / B batch col
    const int q    = lane >> 4;
    // value-lane mapping (epilogue): lane = cv*16 + din
    const int cv   = q;               // real batch 0..3
    const int din  = c;               // dim within tile

    // ---- stage X into LDS (compact, 4 cols; shift baked in) ----
    for (int idx = tid; idx < NB * XSLOTS; idx += NTHREADS) {
        int t = idx >> 2, cc = idx & 3;
        int ts = IS_DEC ? (t - 1) : t;
        float x0 = 0.0f, x1 = 0.0f, x2 = 0.0f;
        if (ts >= 0 && ts < T_LEN) {
            const float* xp = X + ((size_t)(g * NB + cc) * T_LEN + ts) * 3;
            x0 = xp[0]; x1 = xp[1]; x2 = xp[2];
        }
        ushortx4 v = {f2bf(x0), f2bf(x1), f2bf(x2), (unsigned short)0x3F80};
        *(ushortx4*)&shX[t * XT + cc * 4] = v;
    }

    // ---- ALL weights resident: 2 tiles x 3 gates x 8 k = 192 regs ----
    shortx8 Wf[2][3][8];   // [hti][r|z|n][k]
    #pragma unroll
    for (int hti = 0; hti < 2; ++hti) {
        int ht = w + hti * 8;
        #pragma unroll
        for (int gg = 0; gg < 3; ++gg) {
            int row = gg * 256 + ht * 16 + c;
            const float* wp = W_hh + (size_t)row * 256 + q * 8;
            #pragma unroll
            for (int k = 0; k < 8; ++k) {
                const f32x4* p = (const f32x4*)(wp + k * 32);
                f32x4 f0 = p[0];
                f32x4 f1 = p[1];
                shortx8 a;
                a[0] = (short)f2bf(f0[0]); a[1] = (short)f2bf(f0[1]);
                a[2] = (short)f2bf(f0[2]); a[3] = (short)f2bf(f0[3]);
                a[4] = (short)f2bf(f1[0]); a[5] = (short)f2bf(f1[1]);
                a[6] = (short)f2bf(f1[2]); a[7] = (short)f2bf(f1[3]);
                Wf[hti][gg][k] = a;
            }
        }
    }

    // ---- x/bias A-frags for gates r,z only (q==0 lanes carry data) ----
#if HAVE_K16
    i16x4 ax[2][2];
#else
    shortx8 ax[2][2];
#endif
    #pragma unroll
    for (int hti = 0; hti < 2; ++hti) {
        int ht = w + hti * 8;
        int rr_ = ht * 16 + c;
        int rowr = rr_, rowz = 256 + rr_;
        short r0 = 0, r1 = 0, r2 = 0, r3 = 0, z0 = 0, z1 = 0, z2 = 0, z3 = 0;
        if (q == 0) {
            r0 = (short)f2bf(W_ih[rowr * 3 + 0]);
            r1 = (short)f2bf(W_ih[rowr * 3 + 1]);
            r2 = (short)f2bf(W_ih[rowr * 3 + 2]);
            r3 = (short)f2bf(b_ih[rowr] + b_hh[rowr]);
            z0 = (short)f2bf(W_ih[rowz * 3 + 0]);
            z1 = (short)f2bf(W_ih[rowz * 3 + 1]);
            z2 = (short)f2bf(W_ih[rowz * 3 + 2]);
            z3 = (short)f2bf(b_ih[rowz] + b_hh[rowz]);
        }
#if HAVE_K16
        ax[hti][0] = i16x4{r0, r1, r2, r3};
        ax[hti][1] = i16x4{z0, z1, z2, z3};
#else
        ax[hti][0] = shortx8{r0, r1, r2, r3, 0, 0, 0, 0};
        ax[hti][1] = shortx8{z0, z1, z2, z3, 0, 0, 0, 0};
#endif
    }

    // ---- value-lane constants: n-gate weights/biases + h offsets ----
    // nx computed scalarly: Wn[j][i] f32 (full precision), bihn folded in.
    float Wn[2][3], bihn[2], bhn[2];
    int offv[2];
    #pragma unroll
    for (int j = 0; j < 2; ++j) {
        int d = (w + j * 8) * 16 + din;
        Wn[j][0] = W_ih[(512 + d) * 3 + 0];
        Wn[j][1] = W_ih[(512 + d) * 3 + 1];
        Wn[j][2] = W_ih[(512 + d) * 3 + 2];
        bihn[j] = b_ih[512 + d];
        bhn[j]  = b_hh[512 + d];
        offv[j] = (d >> 3) * 32 + cv * 8 + (d & 7);
    }

    // ---- init h0: value-lane fp32 carry; bf16 into parity buffer 0 ----
    float hold[2] = {0.0f, 0.0f};
    #pragma unroll
    for (int j = 0; j < 2; ++j) {
        if (IS_DEC) {
            int d = (w + j * 8) * 16 + din;
            size_t gi = (size_t)(g * NB + cv) * HID + d;
            hold[j] = h_in[gi] + noise[gi];
        }
        shH[offv[j]] = f2bf(hold[j]);
    }

    // ---- incremental decoder Y pointer (step stride = NB*HID shorts) ----
    unsigned short* yp = nullptr;
    if (IS_DEC)
        yp = Yout + ((size_t)g * T_LEN * NB + cv) * HID + w * 16 + din;

    __syncthreads();

    const f32x4 zc = {0.0f, 0.0f, 0.0f, 0.0f};
    const shortx8 z8 = {0, 0, 0, 0, 0, 0, 0, 0};

    // ---- x-step for t=0 (C = inline 0 initializes acc r/z) ----
    f32x4 acc[2][3];   // [hti][r, z, nh]
    {
#if HAVE_K16
        i16x4 bx = {0, 0, 0, 0};
        if (c < NB) bx = *(const i16x4*)&shX[c * 4];
        #pragma unroll
        for (int hti = 0; hti < 2; ++hti) {
            acc[hti][0] = MFMA_X(ax[hti][0], bx, zc);
            acc[hti][1] = MFMA_X(ax[hti][1], bx, zc);
        }
#else
        shortx8 bx = z8;
        if (q == 0 && c < NB) {
            ushortx4 xv = *(const ushortx4*)&shX[c * 4];
            bx = shortx8{(short)xv[0], (short)xv[1], (short)xv[2], (short)xv[3],
                         0, 0, 0, 0};
        }
        #pragma unroll
        for (int hti = 0; hti < 2; ++hti) {
            acc[hti][0] = __builtin_amdgcn_mfma_f32_16x16x32_bf16(ax[hti][0], bx, zc, 0, 0, 0);
            acc[hti][1] = __builtin_amdgcn_mfma_f32_16x16x32_bf16(ax[hti][1], bx, zc, 0, 0, 0);
        }
#endif
    }

    const int bbase = q * 32 + c * 8;    // lane's compact B-frag base (c<NB)
    unsigned short* shRd_w = shRd + w * 1024;  // wave-private 2KB scratch
    // swizzled gather offset: e' = cv*16+din; addr = (e'^cv)<<3
    const int rdoff = (((cv * 16 + din) ^ cv) << 3);

    int xidx = XT + c * 4;     // x slot for step t+1 (only read when c<NB)
    int xvidx = cv * 4;        // value-lane x slot for step t

    // ---- recurrence ----
    for (int t = 0; t < T_LEN; ++t) {
        const unsigned short* brow = shH + (t & 1) * HBUF + bbase;
        unsigned short* hn = shH + ((t + 1) & 1) * HBUF;

        // n-gate accumulators start at 0 (biases handled in the epilogue)
        acc[0][2] = zc;
        acc[1][2] = zc;

        // GEMM: all A-frags from regs; shared B-frag predicated (256B/read)
        #pragma unroll
        for (int k = 0; k < 8; ++k) {
            shortx8 bf = z8;
            if (c < NB) bf = *(const shortx8*)(brow + k * 128);
            acc[0][0] = __builtin_amdgcn_mfma_f32_16x16x32_bf16(Wf[0][0][k], bf, acc[0][0], 0, 0, 0);
            acc[1][0] = __builtin_amdgcn_mfma_f32_16x16x32_bf16(Wf[1][0][k], bf, acc[1][0], 0, 0, 0);
            acc[0][1] = __builtin_amdgcn_mfma_f32_16x16x32_bf16(Wf[0][1][k], bf, acc[0][1], 0, 0, 0);
            acc[1][1] = __builtin_amdgcn_mfma_f32_16x16x32_bf16(Wf[1][1][k], bf, acc[1][1], 0, 0, 0);
            acc[0][2] = __builtin_amdgcn_mfma_f32_16x16x32_bf16(Wf[0][2][k], bf, acc[0][2], 0, 0, 0);
            acc[1][2] = __builtin_amdgcn_mfma_f32_16x16x32_bf16(Wf[1][2][k], bf, acc[1][2], 0, 0, 0);
        }

        // ---- scatter gate triples {r,z,nh} to swizzled scratch ----
        // tile region j*512 shorts; entry e = c*16 + q*4 + r, addr (e^c)<<3
        if (c < NB) {
            #pragma unroll
            for (int j = 0; j < 2; ++j) {
                #pragma unroll
                for (int r = 0; r < 4; ++r) {
                    f32x4 v = {acc[j][0][r], acc[j][1][r], acc[j][2][r], 0.0f};
                    int e = c * 16 + q * 4 + r;
                    *(f32x4*)&shRd_w[j * 512 + ((e ^ c) << 3)] = v;
                }
            }
        }

        // value-lane x for THIS step (slot t): one b64 read per lane
        ushortx4 xval = *(const ushortx4*)&shX[xvidx];
        xvidx += XT;

        // bx for step t+1
#if HAVE_K16
        i16x4 bxn = {0, 0, 0, 0};
        if (c < NB) bxn = *(const i16x4*)&shX[xidx];
#else
        shortx8 bxn = z8;
        if (q == 0 && c < NB) {
            ushortx4 xvn = *(const ushortx4*)&shX[xidx];
            bxn = shortx8{(short)xvn[0], (short)xvn[1], (short)xvn[2], (short)xvn[3],
                          0, 0, 0, 0};
        }
#endif
        xidx += XT;

        // x-step re-init for t+1, gates r,z (independent MFMAs hide waits)
#if HAVE_K16
        #pragma unroll
        for (int hti = 0; hti < 2; ++hti) {
            acc[hti][0] = MFMA_X(ax[hti][0], bxn, zc);
            acc[hti][1] = MFMA_X(ax[hti][1], bxn, zc);
        }
#else
        #pragma unroll
        for (int hti = 0; hti < 2; ++hti) {
            acc[hti][0] = __builtin_amdgcn_mfma_f32_16x16x32_bf16(ax[hti][0], bxn, zc, 0, 0, 0);
            acc[hti][1] = __builtin_amdgcn_mfma_f32_16x16x32_bf16(ax[hti][1], bxn, zc, 0, 0, 0);
        }
#endif

        // ---- value-lane epilogue: TWO values per lane (12 trans) ----
        {
            float x0 = bf2f(xval[0]), x1 = bf2f(xval[1]), x2 = bf2f(xval[2]);
            #pragma unroll
            for (int j = 0; j < 2; ++j) {
                f32x4 av = *(const f32x4*)&shRd_w[j * 512 + rdoff];  // {r,z,nh}
                float nx = Wn[j][0] * x0 + Wn[j][1] * x1 + Wn[j][2] * x2 + bihn[j];
                float rr = sigmoid_(av[0]);
                float zz = sigmoid_(av[1]);
                float nn = tanh_(nx + rr * (av[2] + bhn[j]));
                float ho = nn + zz * (hold[j] - nn);
                hold[j] = ho;
                unsigned short hb = f2bf(ho);
                hn[offv[j]] = hb;
                if (IS_DEC) yp[j * 128] = hb;
            }
        }
        if (IS_DEC) yp += NB * HID;   // stride NB*256 shorts per step
        __syncthreads();
    }

    if (!IS_DEC) {
        // hand the decoder the EXACT fp32 final h (value-lane stores)
        #pragma unroll
        for (int j = 0; j < 2; ++j) {
            int d = (w + j * 8) * 16 + din;
            h_out[(size_t)(g * NB + cv) * HID + d] = hold[j];
        }
    }
}

// out[b][t][d] = sum_h Y[g][t][b4][h] * W_fc[d][h] + b_fc[d]
// Y layout: [128][256][4][256]
__global__ __launch_bounds__(256) void proj_kernel(
    const unsigned short* __restrict__ Y, const float* __restrict__ W_fc,
    const float* __restrict__ b_fc, float* __restrict__ out)
{
    int row = blockIdx.x * 256 + threadIdx.x;  // ((g*T + t)*NB + b4)
    int b4 = row & (NB - 1);
    int gt = row >> 2;                         // g*T + t
    int t = gt & (T_LEN - 1);
    int g = gt >> 8;
    const unsigned short* y = Y + (size_t)row * HID;
    float a0 = b_fc[0], a1 = b_fc[1], a2 = b_fc[2];
    #pragma unroll 4
    for (int k8 = 0; k8 < 32; ++k8) {
        ushortx8 v = *(const ushortx8*)(y + k8 * 8);
        #pragma unroll
        for (int j = 0; j < 8; ++j) {
            float f = bf2f(v[j]);
            int k = k8 * 8 + j;
            a0 += f * W_fc[k];          // uniform -> scalar loads
            a1 += f * W_fc[256 + k];
            a2 += f * W_fc[512 + k];
        }
    }
    int batch = g * NB + b4;
    float* o = out + ((size_t)batch * T_LEN + t) * 3;
    o[0] = a0; o[1] = a1; o[2] = a2;
}

extern "C" void kernel_launch(void* const* d_in, const int* in_sizes, int n_in,
                              void* d_out, int out_size, void* d_ws, size_t ws_size,
                              hipStream_t stream)
{
    const float* X_p      = (const float*)d_in[0];
    const float* X_f      = (const float*)d_in[1];
    const float* noise    = (const float*)d_in[2];
    const float* W_ih_enc = (const float*)d_in[3];
    const float* W_hh_enc = (const float*)d_in[4];
    const float* b_ih_enc = (const float*)d_in[5];
    const float* b_hh_enc = (const float*)d_in[6];
    const float* W_ih_dec = (const float*)d_in[7];
    const float* W_hh_dec = (const float*)d_in[8];
    const float* b_ih_dec = (const float*)d_in[9];
    const float* b_hh_dec = (const float*)d_in[10];
    const float* W_fc     = (const float*)d_in[11];
    const float* b_fc     = (const float*)d_in[12];

    // ws: [0,512K) h_enc fp32 | [512K, +67.1MB) decoder Y bf16
    float* h_enc = (float*)d_ws;
    unsigned short* Yws = (unsigned short*)((char*)d_ws + (512u << 10));

    hipLaunchKernelGGL((gru_persistent<0>), dim3(NBLK), dim3(NTHREADS), SMEM_BYTES, stream,
        X_p, W_hh_enc, W_ih_enc, b_ih_enc, b_hh_enc,
        (const float*)nullptr, (const float*)nullptr, h_enc,
        (unsigned short*)nullptr);

    hipLaunchKernelGGL((gru_persistent<1>), dim3(NBLK), dim3(NTHREADS), SMEM_BYTES, stream,
        X_f, W_hh_dec, W_ih_dec, b_ih_dec, b_hh_dec,
        h_enc, noise, (float*)nullptr, Yws);

    hipLaunchKernelGGL(proj_kernel, dim3((B_TOT * T_LEN) / 256), dim3(256), 0, stream,
        Yws, W_fc, b_fc, (float*)d_out);
}

// Round 11
// 934.627 us; speedup vs baseline: 1.3381x; 1.3381x over previous
//
#include <hip/hip_runtime.h>

// NetG: seq2seq GRU (enc GRU -> +noise -> dec GRU -> FC head)
// B=512, T=256, H=256, D=3.
//
// R22 = R12's PROVEN register recipe x R19/R21's verified cheap step,
//       at 128 blocks.
//   R21 post-mortem: allocator caps arch VGPRs at 128 for 8-wave blocks
//   regardless of launch_bounds; 192-reg all-resident Wf spills ~84MB and
//   serializes each step on scratch vmcnt. R12 (Wf=128 z,n resident +
//   gate-r split LDS/global, acc in AGPRs) ran CLEAN at the same reported
//   VGPR=128. Rule: never exceed R12's register mix.
//   Kept from R19/R21 (measured clean): NB=4 / 128 blocks; compact h
//   (2x1024 shorts, predicated 256B bf reads); swizzled wave-private
//   scratch (0 bank conflicts); value-lane epilogue (12 trans/wave);
//   scalar-f32 nx (no acc3, no n-gate x-init MFMAs); fp32 value-lane h
//   carry; one barrier/step.
//   Kept from R12 (proven): gate-r k=0..3 LDS frags (64KB, staged once),
//   k=4..7 global prefetch via prep_wr (issued at step start, consumed
//   after the LDS half); z,n A-frags resident (128 regs); 512 thr /
//   8 waves, wave owns tiles {w, w+8}.
// LDS: 64KB wr + 4KB h + 8.2KB x + 16KB scratch = 94.2KB (1 block/CU).

#define B_TOT 512
#define T_LEN 256
#define HID 256
#define NBATCH 16              // MFMA column count (cols >= NB are pad)
#define NB 4                   // real batches per block
#define NTHREADS 512           // 8 waves, 2 tiles/wave
#define NBLK (B_TOT / NB)      // 128

#define XSLOTS (T_LEN + 1)
#define XT 16                  // compact x slot: 4 cols x 4 shorts
#define HBUF (NB * HID)        // 1024 shorts per h parity buffer

// LDS partition (units: shorts)
#define WR_OFF 0                         // gate-r k=0..3 frags: 32768
#define H_OFF  32768                     // 2 x 1024
#define X_OFF  34816                     // 257 x 16 = 4112
#define RD_OFF 38928                     // 8 waves x 1024
#define SMEM_SHORTS 47120
#define SMEM_BYTES  (SMEM_SHORTS * 2)    // 94240 B <= 160 KiB

typedef __attribute__((ext_vector_type(4))) float f32x4;
typedef __attribute__((ext_vector_type(8))) short shortx8;
typedef __attribute__((ext_vector_type(4))) short i16x4;
typedef __attribute__((ext_vector_type(4))) unsigned short ushortx4;
typedef __attribute__((ext_vector_type(8))) unsigned short ushortx8;

#if __has_builtin(__builtin_amdgcn_mfma_f32_16x16x16_bf16)
#define HAVE_K16 1
#define MFMA_X(A, B, C) __builtin_amdgcn_mfma_f32_16x16x16_bf16((A), (B), (C), 0, 0, 0)
#elif __has_builtin(__builtin_amdgcn_mfma_f32_16x16x16bf16_1k)
#define HAVE_K16 1
#define MFMA_X(A, B, C) __builtin_amdgcn_mfma_f32_16x16x16bf16_1k((A), (B), (C), 0, 0, 0)
#else
#define HAVE_K16 0
#endif

__device__ __forceinline__ unsigned short f2bf(float x) {
    unsigned u = __float_as_uint(x);
    u += 0x7FFF + ((u >> 16) & 1);   // RNE
    return (unsigned short)(u >> 16);
}
__device__ __forceinline__ float bf2f(unsigned short s) {
    return __uint_as_float(((unsigned)s) << 16);
}
__device__ __forceinline__ float fastrcp(float x) {
#if __has_builtin(__builtin_amdgcn_rcpf)
    return __builtin_amdgcn_rcpf(x);
#else
    return 1.0f / x;
#endif
}
__device__ __forceinline__ float exp2raw(float y) {
#if __has_builtin(__builtin_amdgcn_exp2f)
    return __builtin_amdgcn_exp2f(y);
#else
    return __expf(y * 0.69314718056f);
#endif
}
__device__ __forceinline__ float sigmoid_(float x) {
    return fastrcp(1.0f + exp2raw(x * -1.44269504f));
}
__device__ __forceinline__ float tanh_(float x) {
    return 2.0f * fastrcp(1.0f + exp2raw(x * -2.88539008f)) - 1.0f;
}

// Pack gate-r (rows 0..255 of W_hh), K-half k=4..7, into per-lane fragment
// layout: dst[((ht*4+kk)*64+lane)*8+j] = bf16(W[ht*16+(lane&15)][(kk+4)*32+(lane>>4)*8+j])
__global__ __launch_bounds__(256) void prep_wr(
    const float* __restrict__ Whh_enc, const float* __restrict__ Whh_dec,
    unsigned short* __restrict__ wr_enc, unsigned short* __restrict__ wr_dec)
{
    int idx = blockIdx.x * 256 + threadIdx.x;    // 0..8191
    int gru = idx >> 12;
    int rem = idx & 4095;                        // (ht*4+kk)*64 + lane
    int lane = rem & 63;
    int kk = (rem >> 6) & 3;
    int ht = rem >> 8;
    const float* W = gru ? Whh_dec : Whh_enc;
    unsigned short* dst = gru ? wr_dec : wr_enc;
    int row = ht * 16 + (lane & 15);
    int col = (kk + 4) * 32 + (lane >> 4) * 8;
    const float* src = W + (size_t)row * 256 + col;
    ushortx8 v;
    #pragma unroll
    for (int j = 0; j < 8; ++j) v[j] = f2bf(src[j]);
    *(ushortx8*)(dst + (size_t)rem * 8) = v;
}

template<int IS_DEC>
__global__ __launch_bounds__(NTHREADS, 1) void gru_persistent(
    const float* __restrict__ X,       // [512][256][3]
    const float* __restrict__ W_hh,    // [768][256] gates r,z,n
    const float* __restrict__ W_ih,    // [768][3]
    const float* __restrict__ b_ih,    // [768]
    const float* __restrict__ b_hh,    // [768]
    const unsigned short* __restrict__ Wr4, // gate-r k=4..7 frags (prep_wr)
    const float* __restrict__ h_in,    // dec: [512][256] fp32; enc: null
    const float* __restrict__ noise,   // dec: [512][256]; enc: null
    float* __restrict__ h_out,         // enc: [512][256] fp32; dec: null
    unsigned short* __restrict__ Yout) // dec: [128][256][4][256] bf16
{
    extern __shared__ unsigned short smem[];
    unsigned short* shWr = smem + WR_OFF;
    unsigned short* shH  = smem + H_OFF;   // 2 compact parity buffers
    unsigned short* shX  = smem + X_OFF;
    unsigned short* shRd = smem + RD_OFF;

    const int tid  = threadIdx.x;
    const int g    = blockIdx.x;
    const int w    = tid >> 6;        // wave 0..7; owns tiles {w, w+8}
    const int lane = tid & 63;
    const int c    = lane & 15;       // GEMM: A-row within tile / B batch col
    const int q    = lane >> 4;
    // value-lane mapping (epilogue): lane = cv*16 + din
    const int cv   = q;               // real batch 0..3
    const int din  = c;               // dim within tile

    // ---- stage X into LDS (compact, 4 cols; shift baked in) ----
    for (int idx = tid; idx < NB * XSLOTS; idx += NTHREADS) {
        int t = idx >> 2, cc = idx & 3;
        int ts = IS_DEC ? (t - 1) : t;
        float x0 = 0.0f, x1 = 0.0f, x2 = 0.0f;
        if (ts >= 0 && ts < T_LEN) {
            const float* xp = X + ((size_t)(g * NB + cc) * T_LEN + ts) * 3;
            x0 = xp[0]; x1 = xp[1]; x2 = xp[2];
        }
        ushortx4 v = {f2bf(x0), f2bf(x1), f2bf(x2), (unsigned short)0x3F80};
        *(ushortx4*)&shX[t * XT + cc * 4] = v;
    }

    // ---- gate-r k=0..3 frags -> LDS (each wave stages its 2 tiles) ----
    #pragma unroll
    for (int hti = 0; hti < 2; ++hti) {
        int ht = w + hti * 8;
        int row = ht * 16 + c;                      // gate r
        const float* wp = W_hh + (size_t)row * 256 + q * 8;
        #pragma unroll
        for (int k = 0; k < 4; ++k) {
            const f32x4* p = (const f32x4*)(wp + k * 32);
            f32x4 f0 = p[0];
            f32x4 f1 = p[1];
            shortx8 a;
            a[0] = (short)f2bf(f0[0]); a[1] = (short)f2bf(f0[1]);
            a[2] = (short)f2bf(f0[2]); a[3] = (short)f2bf(f0[3]);
            a[4] = (short)f2bf(f1[0]); a[5] = (short)f2bf(f1[1]);
            a[6] = (short)f2bf(f1[2]); a[7] = (short)f2bf(f1[3]);
            *(shortx8*)&shWr[((ht * 4 + k) * 64 + lane) * 8] = a;
        }
    }

    // ---- gates z,n A-frags resident (R12's proven 128-reg footprint) ----
    shortx8 Wf[2][2][8];   // [hti][z|n][k]
    #pragma unroll
    for (int hti = 0; hti < 2; ++hti) {
        int ht = w + hti * 8;
        #pragma unroll
        for (int gg = 0; gg < 2; ++gg) {
            int row = (gg + 1) * 256 + ht * 16 + c;
            const float* wp = W_hh + (size_t)row * 256 + q * 8;
            #pragma unroll
            for (int k = 0; k < 8; ++k) {
                const f32x4* p = (const f32x4*)(wp + k * 32);
                f32x4 f0 = p[0];
                f32x4 f1 = p[1];
                shortx8 a;
                a[0] = (short)f2bf(f0[0]); a[1] = (short)f2bf(f0[1]);
                a[2] = (short)f2bf(f0[2]); a[3] = (short)f2bf(f0[3]);
                a[4] = (short)f2bf(f1[0]); a[5] = (short)f2bf(f1[1]);
                a[6] = (short)f2bf(f1[2]); a[7] = (short)f2bf(f1[3]);
                Wf[hti][gg][k] = a;
            }
        }
    }

    // ---- x/bias A-frags for gates r,z only (q==0 lanes carry data) ----
#if HAVE_K16
    i16x4 ax[2][2];
#else
    shortx8 ax[2][2];
#endif
    #pragma unroll
    for (int hti = 0; hti < 2; ++hti) {
        int ht = w + hti * 8;
        int rr_ = ht * 16 + c;
        int rowr = rr_, rowz = 256 + rr_;
        short r0 = 0, r1 = 0, r2 = 0, r3 = 0, z0 = 0, z1 = 0, z2 = 0, z3 = 0;
        if (q == 0) {
            r0 = (short)f2bf(W_ih[rowr * 3 + 0]);
            r1 = (short)f2bf(W_ih[rowr * 3 + 1]);
            r2 = (short)f2bf(W_ih[rowr * 3 + 2]);
            r3 = (short)f2bf(b_ih[rowr] + b_hh[rowr]);
            z0 = (short)f2bf(W_ih[rowz * 3 + 0]);
            z1 = (short)f2bf(W_ih[rowz * 3 + 1]);
            z2 = (short)f2bf(W_ih[rowz * 3 + 2]);
            z3 = (short)f2bf(b_ih[rowz] + b_hh[rowz]);
        }
#if HAVE_K16
        ax[hti][0] = i16x4{r0, r1, r2, r3};
        ax[hti][1] = i16x4{z0, z1, z2, z3};
#else
        ax[hti][0] = shortx8{r0, r1, r2, r3, 0, 0, 0, 0};
        ax[hti][1] = shortx8{z0, z1, z2, z3, 0, 0, 0, 0};
#endif
    }

    // ---- value-lane constants: n-gate weights/biases + h offsets ----
    float Wn[2][3], bihn[2], bhn[2];
    int offv[2];
    #pragma unroll
    for (int j = 0; j < 2; ++j) {
        int d = (w + j * 8) * 16 + din;
        Wn[j][0] = W_ih[(512 + d) * 3 + 0];
        Wn[j][1] = W_ih[(512 + d) * 3 + 1];
        Wn[j][2] = W_ih[(512 + d) * 3 + 2];
        bihn[j] = b_ih[512 + d];
        bhn[j]  = b_hh[512 + d];
        offv[j] = (d >> 3) * 32 + cv * 8 + (d & 7);
    }

    // ---- init h0: value-lane fp32 carry; bf16 into parity buffer 0 ----
    float hold[2] = {0.0f, 0.0f};
    #pragma unroll
    for (int j = 0; j < 2; ++j) {
        if (IS_DEC) {
            int d = (w + j * 8) * 16 + din;
            size_t gi = (size_t)(g * NB + cv) * HID + d;
            hold[j] = h_in[gi] + noise[gi];
        }
        shH[offv[j]] = f2bf(hold[j]);
    }

    // ---- incremental decoder Y pointer (step stride = NB*HID shorts) ----
    unsigned short* yp = nullptr;
    if (IS_DEC)
        yp = Yout + ((size_t)g * T_LEN * NB + cv) * HID + w * 16 + din;

    __syncthreads();

    const f32x4 zc = {0.0f, 0.0f, 0.0f, 0.0f};
    const shortx8 z8 = {0, 0, 0, 0, 0, 0, 0, 0};

    // ---- x-step for t=0 (C = inline 0 initializes acc r/z) ----
    f32x4 acc[2][3];   // [hti][r, z, nh]
    {
#if HAVE_K16
        i16x4 bx = {0, 0, 0, 0};
        if (c < NB) bx = *(const i16x4*)&shX[c * 4];
        #pragma unroll
        for (int hti = 0; hti < 2; ++hti) {
            acc[hti][0] = MFMA_X(ax[hti][0], bx, zc);
            acc[hti][1] = MFMA_X(ax[hti][1], bx, zc);
        }
#else
        shortx8 bx = z8;
        if (q == 0 && c < NB) {
            ushortx4 xv = *(const ushortx4*)&shX[c * 4];
            bx = shortx8{(short)xv[0], (short)xv[1], (short)xv[2], (short)xv[3],
                         0, 0, 0, 0};
        }
        #pragma unroll
        for (int hti = 0; hti < 2; ++hti) {
            acc[hti][0] = __builtin_amdgcn_mfma_f32_16x16x32_bf16(ax[hti][0], bx, zc, 0, 0, 0);
            acc[hti][1] = __builtin_amdgcn_mfma_f32_16x16x32_bf16(ax[hti][1], bx, zc, 0, 0, 0);
        }
#endif
    }

    const int bbase = q * 32 + c * 8;    // lane's compact B-frag base (c<NB)
    const unsigned short* ab0 = shWr + ((size_t)(w * 4) * 64 + lane) * 8;
    const unsigned short* ab1 = shWr + ((size_t)((w + 8) * 4) * 64 + lane) * 8;
    const unsigned short* gb0 = Wr4 + ((size_t)(w * 4) * 64 + lane) * 8;
    const unsigned short* gb1 = Wr4 + ((size_t)((w + 8) * 4) * 64 + lane) * 8;
    unsigned short* shRd_w = shRd + w * 1024;  // wave-private 2KB scratch
    const int rdoff = (((cv * 16 + din) ^ cv) << 3);  // swizzled gather

    int xidx = XT + c * 4;     // x slot for step t+1 (only read when c<NB)
    int xvidx = cv * 4;        // value-lane x slot for step t

    // ---- recurrence ----
    for (int t = 0; t < T_LEN; ++t) {
        const unsigned short* brow = shH + (t & 1) * HBUF + bbase;
        unsigned short* hn = shH + ((t + 1) & 1) * HBUF;

        // gate-r k=4..7 from global: issued at step start, consumed after
        // the LDS half (R6/R12's proven prefetch timing)
        shortx8 gr0[4], gr1[4];
        #pragma unroll
        for (int kk = 0; kk < 4; ++kk) {
            gr0[kk] = *(const shortx8*)(gb0 + kk * 512);
            gr1[kk] = *(const shortx8*)(gb1 + kk * 512);
        }

        // n-gate accumulators start at 0 (biases handled in the epilogue)
        acc[0][2] = zc;
        acc[1][2] = zc;

        // k=0..3: gate-r from LDS frags
        #pragma unroll
        for (int k = 0; k < 4; ++k) {
            shortx8 bf = z8;
            if (c < NB) bf = *(const shortx8*)(brow + k * 128);
            shortx8 ar0 = *(const shortx8*)(ab0 + k * 512);
            shortx8 ar1 = *(const shortx8*)(ab1 + k * 512);
            acc[0][0] = __builtin_amdgcn_mfma_f32_16x16x32_bf16(ar0,         bf, acc[0][0], 0, 0, 0);
            acc[1][0] = __builtin_amdgcn_mfma_f32_16x16x32_bf16(ar1,         bf, acc[1][0], 0, 0, 0);
            acc[0][1] = __builtin_amdgcn_mfma_f32_16x16x32_bf16(Wf[0][0][k], bf, acc[0][1], 0, 0, 0);
            acc[1][1] = __builtin_amdgcn_mfma_f32_16x16x32_bf16(Wf[1][0][k], bf, acc[1][1], 0, 0, 0);
            acc[0][2] = __builtin_amdgcn_mfma_f32_16x16x32_bf16(Wf[0][1][k], bf, acc[0][2], 0, 0, 0);
            acc[1][2] = __builtin_amdgcn_mfma_f32_16x16x32_bf16(Wf[1][1][k], bf, acc[1][2], 0, 0, 0);
        }
        // k=4..7: gate-r from the global prefetch
        #pragma unroll
        for (int k = 4; k < 8; ++k) {
            shortx8 bf = z8;
            if (c < NB) bf = *(const shortx8*)(brow + k * 128);
            acc[0][0] = __builtin_amdgcn_mfma_f32_16x16x32_bf16(gr0[k - 4],  bf, acc[0][0], 0, 0, 0);
            acc[1][0] = __builtin_amdgcn_mfma_f32_16x16x32_bf16(gr1[k - 4],  bf, acc[1][0], 0, 0, 0);
            acc[0][1] = __builtin_amdgcn_mfma_f32_16x16x32_bf16(Wf[0][0][k], bf, acc[0][1], 0, 0, 0);
            acc[1][1] = __builtin_amdgcn_mfma_f32_16x16x32_bf16(Wf[1][0][k], bf, acc[1][1], 0, 0, 0);
            acc[0][2] = __builtin_amdgcn_mfma_f32_16x16x32_bf16(Wf[0][1][k], bf, acc[0][2], 0, 0, 0);
            acc[1][2] = __builtin_amdgcn_mfma_f32_16x16x32_bf16(Wf[1][1][k], bf, acc[1][2], 0, 0, 0);
        }

        // ---- scatter gate triples {r,z,nh} to swizzled scratch ----
        if (c < NB) {
            #pragma unroll
            for (int j = 0; j < 2; ++j) {
                #pragma unroll
                for (int r = 0; r < 4; ++r) {
                    f32x4 v = {acc[j][0][r], acc[j][1][r], acc[j][2][r], 0.0f};
                    int e = c * 16 + q * 4 + r;
                    *(f32x4*)&shRd_w[j * 512 + ((e ^ c) << 3)] = v;
                }
            }
        }

        // value-lane x for THIS step (slot t): one b64 read per lane
        ushortx4 xval = *(const ushortx4*)&shX[xvidx];
        xvidx += XT;

        // bx for step t+1
#if HAVE_K16
        i16x4 bxn = {0, 0, 0, 0};
        if (c < NB) bxn = *(const i16x4*)&shX[xidx];
#else
        shortx8 bxn = z8;
        if (q == 0 && c < NB) {
            ushortx4 xvn = *(const ushortx4*)&shX[xidx];
            bxn = shortx8{(short)xvn[0], (short)xvn[1], (short)xvn[2], (short)xvn[3],
                          0, 0, 0, 0};
        }
#endif
        xidx += XT;

        // x-step re-init for t+1, gates r,z (independent MFMAs hide waits)
#if HAVE_K16
        #pragma unroll
        for (int hti = 0; hti < 2; ++hti) {
            acc[hti][0] = MFMA_X(ax[hti][0], bxn, zc);
            acc[hti][1] = MFMA_X(ax[hti][1], bxn, zc);
        }
#else
        #pragma unroll
        for (int hti = 0; hti < 2; ++hti) {
            acc[hti][0] = __builtin_amdgcn_mfma_f32_16x16x32_bf16(ax[hti][0], bxn, zc, 0, 0, 0);
            acc[hti][1] = __builtin_amdgcn_mfma_f32_16x16x32_bf16(ax[hti][1], bxn, zc, 0, 0, 0);
        }
#endif

        // ---- value-lane epilogue: TWO values per lane (12 trans) ----
        {
            float x0 = bf2f(xval[0]), x1 = bf2f(xval[1]), x2 = bf2f(xval[2]);
            #pragma unroll
            for (int j = 0; j < 2; ++j) {
                f32x4 av = *(const f32x4*)&shRd_w[j * 512 + rdoff];  // {r,z,nh}
                float nx = Wn[j][0] * x0 + Wn[j][1] * x1 + Wn[j][2] * x2 + bihn[j];
                float rr = sigmoid_(av[0]);
                float zz = sigmoid_(av[1]);
                float nn = tanh_(nx + rr * (av[2] + bhn[j]));
                float ho = nn + zz * (hold[j] - nn);
                hold[j] = ho;
                unsigned short hb = f2bf(ho);
                hn[offv[j]] = hb;
                if (IS_DEC) yp[j * 128] = hb;
            }
        }
        if (IS_DEC) yp += NB * HID;   // stride NB*256 shorts per step
        __syncthreads();
    }

    if (!IS_DEC) {
        // hand the decoder the EXACT fp32 final h (value-lane stores)
        #pragma unroll
        for (int j = 0; j < 2; ++j) {
            int d = (w + j * 8) * 16 + din;
            h_out[(size_t)(g * NB + cv) * HID + d] = hold[j];
        }
    }
}

// out[b][t][d] = sum_h Y[g][t][b4][h] * W_fc[d][h] + b_fc[d]
// Y layout: [128][256][4][256]
__global__ __launch_bounds__(256) void proj_kernel(
    const unsigned short* __restrict__ Y, const float* __restrict__ W_fc,
    const float* __restrict__ b_fc, float* __restrict__ out)
{
    int row = blockIdx.x * 256 + threadIdx.x;  // ((g*T + t)*NB + b4)
    int b4 = row & (NB - 1);
    int gt = row >> 2;                         // g*T + t
    int t = gt & (T_LEN - 1);
    int g = gt >> 8;
    const unsigned short* y = Y + (size_t)row * HID;
    float a0 = b_fc[0], a1 = b_fc[1], a2 = b_fc[2];
    #pragma unroll 4
    for (int k8 = 0; k8 < 32; ++k8) {
        ushortx8 v = *(const ushortx8*)(y + k8 * 8);
        #pragma unroll
        for (int j = 0; j < 8; ++j) {
            float f = bf2f(v[j]);
            int k = k8 * 8 + j;
            a0 += f * W_fc[k];          // uniform -> scalar loads
            a1 += f * W_fc[256 + k];
            a2 += f * W_fc[512 + k];
        }
    }
    int batch = g * NB + b4;
    float* o = out + ((size_t)batch * T_LEN + t) * 3;
    o[0] = a0; o[1] = a1; o[2] = a2;
}

extern "C" void kernel_launch(void* const* d_in, const int* in_sizes, int n_in,
                              void* d_out, int out_size, void* d_ws, size_t ws_size,
                              hipStream_t stream)
{
    const float* X_p      = (const float*)d_in[0];
    const float* X_f      = (const float*)d_in[1];
    const float* noise    = (const float*)d_in[2];
    const float* W_ih_enc = (const float*)d_in[3];
    const float* W_hh_enc = (const float*)d_in[4];
    const float* b_ih_enc = (const float*)d_in[5];
    const float* b_hh_enc = (const float*)d_in[6];
    const float* W_ih_dec = (const float*)d_in[7];
    const float* W_hh_dec = (const float*)d_in[8];
    const float* b_ih_dec = (const float*)d_in[9];
    const float* b_hh_dec = (const float*)d_in[10];
    const float* W_fc     = (const float*)d_in[11];
    const float* b_fc     = (const float*)d_in[12];

    // allow >64 KiB dynamic LDS (idempotent; host-side, graph-capture safe)
    (void)hipFuncSetAttribute((const void*)&gru_persistent<0>,
                              hipFuncAttributeMaxDynamicSharedMemorySize, SMEM_BYTES);
    (void)hipFuncSetAttribute((const void*)&gru_persistent<1>,
                              hipFuncAttributeMaxDynamicSharedMemorySize, SMEM_BYTES);

    // ws: [0,512K) h_enc fp32 | [512K,576K) Wr_enc | [576K,640K) Wr_dec |
    //     [640K, +67.1MB) decoder Y bf16
    float* h_enc = (float*)d_ws;
    unsigned short* wr_enc = (unsigned short*)((char*)d_ws + (512u << 10));
    unsigned short* wr_dec = (unsigned short*)((char*)d_ws + (576u << 10));
    unsigned short* Yws    = (unsigned short*)((char*)d_ws + (640u << 10));

    hipLaunchKernelGGL(prep_wr, dim3(32), dim3(256), 0, stream,
        W_hh_enc, W_hh_dec, wr_enc, wr_dec);

    hipLaunchKernelGGL((gru_persistent<0>), dim3(NBLK), dim3(NTHREADS), SMEM_BYTES, stream,
        X_p, W_hh_enc, W_ih_enc, b_ih_enc, b_hh_enc, wr_enc,
        (const float*)nullptr, (const float*)nullptr, h_enc,
        (unsigned short*)nullptr);

    hipLaunchKernelGGL((gru_persistent<1>), dim3(NBLK), dim3(NTHREADS), SMEM_BYTES, stream,
        X_f, W_hh_dec, W_ih_dec, b_ih_dec, b_hh_dec, wr_dec,
        h_enc, noise, (float*)nullptr, Yws);

    hipLaunchKernelGGL(proj_kernel, dim3((B_TOT * T_LEN) / 256), dim3(256), 0, stream,
        Yws, W_fc, b_fc, (float*)d_out);
}

// Round 13
// 877.578 us; speedup vs baseline: 1.4251x; 1.0650x over previous
//
#include <hip/hip_runtime.h>

// NetG: seq2seq GRU (enc GRU -> +noise -> dec GRU -> FC head)
// B=512, T=256, H=256, D=3.
//
// R23b = R23 resubmitted verbatim (R12 bench died to a container/infra
//   failure before producing any data; static re-audit found no OOB/hang
//   path. Precedent: R7 infra failure -> identical resubmission passed.)
//
// R23 = R17's no-spill lean-wave recipe x NB=4/128 blocks x R19's
//       verified cheap step.
//   R22 post-mortem: per-CU LDS pipe is the binding resource. R17's
//   3430-cyc step ~= its 2400 cyc/CU of LDS reads (4 full ar + 8 full bf
//   per wave x 16 waves); R22 halved TLP (8 waves) and kept full ar.
//   R17's reg mix (1 tile/wave: z,n resident=64 regs, gate-r LDS/global
//   split) measured VGPR=64, NO spill - the only clean config. Reuse it
//   verbatim; cut LDS with R19's verified pieces.
// Structure: 128 blocks x 1024 thr (16 waves, 4/SIMD), NB=4 real
// batches/block, wave owns tile ht=w. Gate-r k=0..3 LDS frags (staged
// once), k=4..7 global prefetch (prep_wr; issued at step start, consumed
// after the LDS half). Compact h [2 parity][1024] shorts - bf reads
// predicated on c<4 (256B each, -75% LDS vs full width). Swizzled
// wave-private scratch scatter/gather (0 bank conflicts, R19/R22
// measured). Value-lane epilogue: ONE value per lane, 6 trans; scalar
// f32 nx (no acc3, no n-gate x-init MFMA). fp32 value-lane h carry
// (exact). One barrier per step. LDS total 94.2 KB -> 1 block/CU.

#define B_TOT 512
#define T_LEN 256
#define HID 256
#define NBATCH 16              // MFMA column count (cols >= NB are pad)
#define NB 4                   // real batches per block
#define NTHREADS 1024          // 16 waves, 1 tile/wave
#define NBLK (B_TOT / NB)      // 128

#define XSLOTS (T_LEN + 1)
#define XT 16                  // compact x slot: 4 cols x 4 shorts
#define HBUF (NB * HID)        // 1024 shorts per h parity buffer

// LDS partition (units: shorts)
#define WR_OFF 0                         // gate-r k=0..3 frags: 32768
#define H_OFF  32768                     // 2 x 1024
#define X_OFF  34816                     // 257 x 16 = 4112
#define RD_OFF 38928                     // 16 waves x 512
#define SMEM_SHORTS 47120
#define SMEM_BYTES  (SMEM_SHORTS * 2)    // 94240 B <= 160 KiB

typedef __attribute__((ext_vector_type(4))) float f32x4;
typedef __attribute__((ext_vector_type(8))) short shortx8;
typedef __attribute__((ext_vector_type(4))) short i16x4;
typedef __attribute__((ext_vector_type(4))) unsigned short ushortx4;
typedef __attribute__((ext_vector_type(8))) unsigned short ushortx8;

#if __has_builtin(__builtin_amdgcn_mfma_f32_16x16x16_bf16)
#define HAVE_K16 1
#define MFMA_X(A, B, C) __builtin_amdgcn_mfma_f32_16x16x16_bf16((A), (B), (C), 0, 0, 0)
#elif __has_builtin(__builtin_amdgcn_mfma_f32_16x16x16bf16_1k)
#define HAVE_K16 1
#define MFMA_X(A, B, C) __builtin_amdgcn_mfma_f32_16x16x16bf16_1k((A), (B), (C), 0, 0, 0)
#else
#define HAVE_K16 0
#endif

__device__ __forceinline__ unsigned short f2bf(float x) {
    unsigned u = __float_as_uint(x);
    u += 0x7FFF + ((u >> 16) & 1);   // RNE
    return (unsigned short)(u >> 16);
}
__device__ __forceinline__ float bf2f(unsigned short s) {
    return __uint_as_float(((unsigned)s) << 16);
}
__device__ __forceinline__ float fastrcp(float x) {
#if __has_builtin(__builtin_amdgcn_rcpf)
    return __builtin_amdgcn_rcpf(x);
#else
    return 1.0f / x;
#endif
}
__device__ __forceinline__ float exp2raw(float y) {
#if __has_builtin(__builtin_amdgcn_exp2f)
    return __builtin_amdgcn_exp2f(y);
#else
    return __expf(y * 0.69314718056f);
#endif
}
__device__ __forceinline__ float sigmoid_(float x) {
    return fastrcp(1.0f + exp2raw(x * -1.44269504f));
}
__device__ __forceinline__ float tanh_(float x) {
    return 2.0f * fastrcp(1.0f + exp2raw(x * -2.88539008f)) - 1.0f;
}

// Pack gate-r (rows 0..255 of W_hh), K-half k=4..7, into per-lane fragment
// layout: dst[((ht*4+kk)*64+lane)*8+j] = bf16(W[ht*16+(lane&15)][(kk+4)*32+(lane>>4)*8+j])
__global__ __launch_bounds__(256) void prep_wr(
    const float* __restrict__ Whh_enc, const float* __restrict__ Whh_dec,
    unsigned short* __restrict__ wr_enc, unsigned short* __restrict__ wr_dec)
{
    int idx = blockIdx.x * 256 + threadIdx.x;    // 0..8191
    int gru = idx >> 12;
    int rem = idx & 4095;                        // (ht*4+kk)*64 + lane
    int lane = rem & 63;
    int kk = (rem >> 6) & 3;
    int ht = rem >> 8;
    const float* W = gru ? Whh_dec : Whh_enc;
    unsigned short* dst = gru ? wr_dec : wr_enc;
    int row = ht * 16 + (lane & 15);
    int col = (kk + 4) * 32 + (lane >> 4) * 8;
    const float* src = W + (size_t)row * 256 + col;
    ushortx8 v;
    #pragma unroll
    for (int j = 0; j < 8; ++j) v[j] = f2bf(src[j]);
    *(ushortx8*)(dst + (size_t)rem * 8) = v;
}

template<int IS_DEC>
__global__ __launch_bounds__(NTHREADS, 1) void gru_persistent(
    const float* __restrict__ X,       // [512][256][3]
    const float* __restrict__ W_hh,    // [768][256] gates r,z,n
    const float* __restrict__ W_ih,    // [768][3]
    const float* __restrict__ b_ih,    // [768]
    const float* __restrict__ b_hh,    // [768]
    const unsigned short* __restrict__ Wr4, // gate-r k=4..7 frags (prep_wr)
    const float* __restrict__ h_in,    // dec: [512][256] fp32; enc: null
    const float* __restrict__ noise,   // dec: [512][256]; enc: null
    float* __restrict__ h_out,         // enc: [512][256] fp32; dec: null
    unsigned short* __restrict__ Yout) // dec: [128][256][4][256] bf16
{
    extern __shared__ unsigned short smem[];
    unsigned short* shWr = smem + WR_OFF;
    unsigned short* shH  = smem + H_OFF;   // 2 compact parity buffers
    unsigned short* shX  = smem + X_OFF;
    unsigned short* shRd = smem + RD_OFF;

    const int tid  = threadIdx.x;
    const int g    = blockIdx.x;
    const int w    = tid >> 6;        // wave 0..15; owns hidden tile ht = w
    const int lane = tid & 63;
    const int c    = lane & 15;       // GEMM: A-row within tile / B batch col
    const int q    = lane >> 4;
    const int ht   = w;
    // value-lane mapping (epilogue): lane = cv*16 + din
    const int cv   = q;               // real batch 0..3
    const int din  = c;               // dim within tile
    const int d_glob = ht * 16 + din;

    // ---- stage X into LDS (compact, 4 cols; shift baked in) ----
    for (int idx = tid; idx < NB * XSLOTS; idx += NTHREADS) {
        int t = idx >> 2, cc = idx & 3;
        int ts = IS_DEC ? (t - 1) : t;
        float x0 = 0.0f, x1 = 0.0f, x2 = 0.0f;
        if (ts >= 0 && ts < T_LEN) {
            const float* xp = X + ((size_t)(g * NB + cc) * T_LEN + ts) * 3;
            x0 = xp[0]; x1 = xp[1]; x2 = xp[2];
        }
        ushortx4 v = {f2bf(x0), f2bf(x1), f2bf(x2), (unsigned short)0x3F80};
        *(ushortx4*)&shX[t * XT + cc * 4] = v;
    }

    // ---- gate-r k=0..3 frags -> LDS (each wave stages its tile) ----
    {
        int row = ht * 16 + c;                      // gate r
        const float* wp = W_hh + (size_t)row * 256 + q * 8;
        #pragma unroll
        for (int k = 0; k < 4; ++k) {
            const f32x4* p = (const f32x4*)(wp + k * 32);
            f32x4 f0 = p[0];
            f32x4 f1 = p[1];
            shortx8 a;
            a[0] = (short)f2bf(f0[0]); a[1] = (short)f2bf(f0[1]);
            a[2] = (short)f2bf(f0[2]); a[3] = (short)f2bf(f0[3]);
            a[4] = (short)f2bf(f1[0]); a[5] = (short)f2bf(f1[1]);
            a[6] = (short)f2bf(f1[2]); a[7] = (short)f2bf(f1[3]);
            *(shortx8*)&shWr[((ht * 4 + k) * 64 + lane) * 8] = a;
        }
    }

    // ---- gates z,n A-frags resident (R17's proven 64-reg footprint) ----
    shortx8 Wf[2][8];   // [z|n][k]
    #pragma unroll
    for (int gg = 0; gg < 2; ++gg) {
        int row = (gg + 1) * 256 + ht * 16 + c;
        const float* wp = W_hh + (size_t)row * 256 + q * 8;
        #pragma unroll
        for (int k = 0; k < 8; ++k) {
            const f32x4* p = (const f32x4*)(wp + k * 32);
            f32x4 f0 = p[0];
            f32x4 f1 = p[1];
            shortx8 a;
            a[0] = (short)f2bf(f0[0]); a[1] = (short)f2bf(f0[1]);
            a[2] = (short)f2bf(f0[2]); a[3] = (short)f2bf(f0[3]);
            a[4] = (short)f2bf(f1[0]); a[5] = (short)f2bf(f1[1]);
            a[6] = (short)f2bf(f1[2]); a[7] = (short)f2bf(f1[3]);
            Wf[gg][k] = a;
        }
    }

    // ---- x/bias A-frags for gates r,z only (q==0 lanes carry data) ----
#if HAVE_K16
    i16x4 ax[2];
#else
    shortx8 ax[2];
#endif
    {
        int rr_ = ht * 16 + c;
        int rowr = rr_, rowz = 256 + rr_;
        short r0 = 0, r1 = 0, r2 = 0, r3 = 0, z0 = 0, z1 = 0, z2 = 0, z3 = 0;
        if (q == 0) {
            r0 = (short)f2bf(W_ih[rowr * 3 + 0]);
            r1 = (short)f2bf(W_ih[rowr * 3 + 1]);
            r2 = (short)f2bf(W_ih[rowr * 3 + 2]);
            r3 = (short)f2bf(b_ih[rowr] + b_hh[rowr]);
            z0 = (short)f2bf(W_ih[rowz * 3 + 0]);
            z1 = (short)f2bf(W_ih[rowz * 3 + 1]);
            z2 = (short)f2bf(W_ih[rowz * 3 + 2]);
            z3 = (short)f2bf(b_ih[rowz] + b_hh[rowz]);
        }
#if HAVE_K16
        ax[0] = i16x4{r0, r1, r2, r3};
        ax[1] = i16x4{z0, z1, z2, z3};
#else
        ax[0] = shortx8{r0, r1, r2, r3, 0, 0, 0, 0};
        ax[1] = shortx8{z0, z1, z2, z3, 0, 0, 0, 0};
#endif
    }

    // ---- value-lane constants: n-gate weights/biases + h offset ----
    float Wn0 = W_ih[(512 + d_glob) * 3 + 0];
    float Wn1 = W_ih[(512 + d_glob) * 3 + 1];
    float Wn2 = W_ih[(512 + d_glob) * 3 + 2];
    float bihn = b_ih[512 + d_glob];
    float bhn  = b_hh[512 + d_glob];
    const int offv = (d_glob >> 3) * 32 + cv * 8 + (d_glob & 7);

    // ---- init h0: value-lane fp32 carry; bf16 into parity buffer 0 ----
    // 1024 lanes cover all 1024 slots of buffer 0 exactly.
    float hold = 0.0f;
    if (IS_DEC) {
        size_t gi = (size_t)(g * NB + cv) * HID + d_glob;
        hold = h_in[gi] + noise[gi];
    }
    shH[offv] = f2bf(hold);

    // ---- incremental decoder Y pointer (step stride = NB*HID shorts) ----
    unsigned short* yp = nullptr;
    if (IS_DEC)
        yp = Yout + ((size_t)g * T_LEN * NB + cv) * HID + d_glob;

    __syncthreads();

    const f32x4 zc = {0.0f, 0.0f, 0.0f, 0.0f};
    const shortx8 z8 = {0, 0, 0, 0, 0, 0, 0, 0};

    // ---- x-step for t=0 (C = inline 0 initializes acc r/z) ----
    f32x4 acc0, acc1, acc2;   // r, z, nh
    {
#if HAVE_K16
        i16x4 bx = {0, 0, 0, 0};
        if (c < NB) bx = *(const i16x4*)&shX[c * 4];
        acc0 = MFMA_X(ax[0], bx, zc);
        acc1 = MFMA_X(ax[1], bx, zc);
#else
        shortx8 bx = z8;
        if (q == 0 && c < NB) {
            ushortx4 xv = *(const ushortx4*)&shX[c * 4];
            bx = shortx8{(short)xv[0], (short)xv[1], (short)xv[2], (short)xv[3],
                         0, 0, 0, 0};
        }
        acc0 = __builtin_amdgcn_mfma_f32_16x16x32_bf16(ax[0], bx, zc, 0, 0, 0);
        acc1 = __builtin_amdgcn_mfma_f32_16x16x32_bf16(ax[1], bx, zc, 0, 0, 0);
#endif
    }

    const int bbase = q * 32 + c * 8;    // lane's compact B-frag base (c<NB)
    const unsigned short* ab = shWr + ((size_t)(ht * 4) * 64 + lane) * 8;
    const unsigned short* gb = Wr4 + ((size_t)(ht * 4) * 64 + lane) * 8;
    unsigned short* shRd_w = shRd + w * 512;   // wave-private 1KB scratch
    const int rdoff = (((cv * 16 + din) ^ cv) << 3);  // swizzled gather

    int xidx = XT + c * 4;     // x slot for step t+1 (only read when c<NB)
    int xvidx = cv * 4;        // value-lane x slot for step t

    // ---- recurrence ----
    for (int t = 0; t < T_LEN; ++t) {
        const unsigned short* brow = shH + (t & 1) * HBUF + bbase;
        unsigned short* hn = shH + ((t + 1) & 1) * HBUF;

        // gate-r k=4..7 from global: issued at step start, consumed after
        // the LDS half (R6/R12/R17's proven prefetch timing)
        shortx8 gr[4];
        #pragma unroll
        for (int kk = 0; kk < 4; ++kk)
            gr[kk] = *(const shortx8*)(gb + kk * 512);

        // n-gate accumulator starts at 0 (biases handled in the epilogue)
        acc2 = zc;

        // k=0..3: gate-r from LDS frags
        #pragma unroll
        for (int k = 0; k < 4; ++k) {
            shortx8 bf = z8;
            if (c < NB) bf = *(const shortx8*)(brow + k * 128);
            shortx8 ar = *(const shortx8*)(ab + k * 512);
            acc0 = __builtin_amdgcn_mfma_f32_16x16x32_bf16(ar,       bf, acc0, 0, 0, 0);
            acc1 = __builtin_amdgcn_mfma_f32_16x16x32_bf16(Wf[0][k], bf, acc1, 0, 0, 0);
            acc2 = __builtin_amdgcn_mfma_f32_16x16x32_bf16(Wf[1][k], bf, acc2, 0, 0, 0);
        }
        // k=4..7: gate-r from the global prefetch
        #pragma unroll
        for (int k = 4; k < 8; ++k) {
            shortx8 bf = z8;
            if (c < NB) bf = *(const shortx8*)(brow + k * 128);
            acc0 = __builtin_amdgcn_mfma_f32_16x16x32_bf16(gr[k - 4], bf, acc0, 0, 0, 0);
            acc1 = __builtin_amdgcn_mfma_f32_16x16x32_bf16(Wf[0][k],  bf, acc1, 0, 0, 0);
            acc2 = __builtin_amdgcn_mfma_f32_16x16x32_bf16(Wf[1][k],  bf, acc2, 0, 0, 0);
        }

        // ---- scatter gate triples {r,z,nh} to swizzled scratch ----
        // entry e = c*16 + q*4 + r; addr (e^c)<<3 -> 2-way banks (free)
        if (c < NB) {
            #pragma unroll
            for (int r = 0; r < 4; ++r) {
                f32x4 v = {acc0[r], acc1[r], acc2[r], 0.0f};
                int e = c * 16 + q * 4 + r;
                *(f32x4*)&shRd_w[(e ^ c) << 3] = v;
            }
        }

        // value-lane x for THIS step (slot t): one b64 read per lane
        ushortx4 xval = *(const ushortx4*)&shX[xvidx];
        xvidx += XT;

        // bx for step t+1
#if HAVE_K16
        i16x4 bxn = {0, 0, 0, 0};
        if (c < NB) bxn = *(const i16x4*)&shX[xidx];
#else
        shortx8 bxn = z8;
        if (q == 0 && c < NB) {
            ushortx4 xvn = *(const ushortx4*)&shX[xidx];
            bxn = shortx8{(short)xvn[0], (short)xvn[1], (short)xvn[2], (short)xvn[3],
                          0, 0, 0, 0};
        }
#endif
        xidx += XT;

        // x-step re-init for t+1, gates r,z (independent MFMAs hide waits)
#if HAVE_K16
        acc0 = MFMA_X(ax[0], bxn, zc);
        acc1 = MFMA_X(ax[1], bxn, zc);
#else
        acc0 = __builtin_amdgcn_mfma_f32_16x16x32_bf16(ax[0], bxn, zc, 0, 0, 0);
        acc1 = __builtin_amdgcn_mfma_f32_16x16x32_bf16(ax[1], bxn, zc, 0, 0, 0);
#endif

        // ---- value-lane epilogue: ONE value per lane (6 trans) ----
        {
            f32x4 av = *(const f32x4*)&shRd_w[rdoff];   // {r,z,nh}
            float x0 = bf2f(xval[0]), x1 = bf2f(xval[1]), x2 = bf2f(xval[2]);
            float nx = Wn0 * x0 + Wn1 * x1 + Wn2 * x2 + bihn;
            float rr = sigmoid_(av[0]);
            float zz = sigmoid_(av[1]);
            float nn = tanh_(nx + rr * (av[2] + bhn));
            float ho = nn + zz * (hold - nn);
            hold = ho;
            unsigned short hb = f2bf(ho);
            hn[offv] = hb;
            if (IS_DEC) {
                *yp = hb;
                yp += NB * HID;   // stride NB*256 shorts per step
            }
        }
        __syncthreads();
    }

    if (!IS_DEC) {
        // hand the decoder the EXACT fp32 final h (value-lane store)
        h_out[(size_t)(g * NB + cv) * HID + d_glob] = hold;
    }
}

// out[b][t][d] = sum_h Y[g][t][b4][h] * W_fc[d][h] + b_fc[d]
// Y layout: [128][256][4][256]
__global__ __launch_bounds__(256) void proj_kernel(
    const unsigned short* __restrict__ Y, const float* __restrict__ W_fc,
    const float* __restrict__ b_fc, float* __restrict__ out)
{
    int row = blockIdx.x * 256 + threadIdx.x;  // ((g*T + t)*NB + b4)
    int b4 = row & (NB - 1);
    int gt = row >> 2;                         // g*T + t
    int t = gt & (T_LEN - 1);
    int g = gt >> 8;
    const unsigned short* y = Y + (size_t)row * HID;
    float a0 = b_fc[0], a1 = b_fc[1], a2 = b_fc[2];
    #pragma unroll 4
    for (int k8 = 0; k8 < 32; ++k8) {
        ushortx8 v = *(const ushortx8*)(y + k8 * 8);
        #pragma unroll
        for (int j = 0; j < 8; ++j) {
            float f = bf2f(v[j]);
            int k = k8 * 8 + j;
            a0 += f * W_fc[k];          // uniform -> scalar loads
            a1 += f * W_fc[256 + k];
            a2 += f * W_fc[512 + k];
        }
    }
    int batch = g * NB + b4;
    float* o = out + ((size_t)batch * T_LEN + t) * 3;
    o[0] = a0; o[1] = a1; o[2] = a2;
}

extern "C" void kernel_launch(void* const* d_in, const int* in_sizes, int n_in,
                              void* d_out, int out_size, void* d_ws, size_t ws_size,
                              hipStream_t stream)
{
    const float* X_p      = (const float*)d_in[0];
    const float* X_f      = (const float*)d_in[1];
    const float* noise    = (const float*)d_in[2];
    const float* W_ih_enc = (const float*)d_in[3];
    const float* W_hh_enc = (const float*)d_in[4];
    const float* b_ih_enc = (const float*)d_in[5];
    const float* b_hh_enc = (const float*)d_in[6];
    const float* W_ih_dec = (const float*)d_in[7];
    const float* W_hh_dec = (const float*)d_in[8];
    const float* b_ih_dec = (const float*)d_in[9];
    const float* b_hh_dec = (const float*)d_in[10];
    const float* W_fc     = (const float*)d_in[11];
    const float* b_fc     = (const float*)d_in[12];

    // allow >64 KiB dynamic LDS (idempotent; host-side, graph-capture safe)
    (void)hipFuncSetAttribute((const void*)&gru_persistent<0>,
                              hipFuncAttributeMaxDynamicSharedMemorySize, SMEM_BYTES);
    (void)hipFuncSetAttribute((const void*)&gru_persistent<1>,
                              hipFuncAttributeMaxDynamicSharedMemorySize, SMEM_BYTES);

    // ws: [0,512K) h_enc fp32 | [512K,576K) Wr_enc | [576K,640K) Wr_dec |
    //     [640K, +67.1MB) decoder Y bf16
    float* h_enc = (float*)d_ws;
    unsigned short* wr_enc = (unsigned short*)((char*)d_ws + (512u << 10));
    unsigned short* wr_dec = (unsigned short*)((char*)d_ws + (576u << 10));
    unsigned short* Yws    = (unsigned short*)((char*)d_ws + (640u << 10));

    hipLaunchKernelGGL(prep_wr, dim3(32), dim3(256), 0, stream,
        W_hh_enc, W_hh_dec, wr_enc, wr_dec);

    hipLaunchKernelGGL((gru_persistent<0>), dim3(NBLK), dim3(NTHREADS), SMEM_BYTES, stream,
        X_p, W_hh_enc, W_ih_enc, b_ih_enc, b_hh_enc, wr_enc,
        (const float*)nullptr, (const float*)nullptr, h_enc,
        (unsigned short*)nullptr);

    hipLaunchKernelGGL((gru_persistent<1>), dim3(NBLK), dim3(NTHREADS), SMEM_BYTES, stream,
        X_f, W_hh_dec, W_ih_dec, b_ih_dec, b_hh_dec, wr_dec,
        h_enc, noise, (float*)nullptr, Yws);

    hipLaunchKernelGGL(proj_kernel, dim3((B_TOT * T_LEN) / 256), dim3(256), 0, stream,
        Yws, W_fc, b_fc, (float*)d_out);
}

// Round 14
// 813.322 us; speedup vs baseline: 1.5377x; 1.0790x over previous
//
#include <hip/hip_runtime.h>

// NetG: seq2seq GRU (enc GRU -> +noise -> dec GRU -> FC head)
// B=512, T=256, H=256, D=3.
//
// R24 = R17 (session-best 806.8us: 366us/GRU, the measured optimum of
//   this design space) FUSED into one launch.
//   R23 post-mortem closed the CU-scaling program: at 16-wave blocks the
//   allocator packs 128 unified regs/wave (64 arch + 64 AGPR Wf) - R17
//   is exactly at cap; every register-adding variant spilled, every
//   batch-split variant added critical-path work (step pinned 3400-4400
//   cyc: LDS ~73% / VALU 58% / MFMA 50% of active CU - balanced soup,
//   bounded by the 16-wave redundant h-read through the LDS pipe).
//   R24 keeps R17's inner loop BYTE-IDENTICAL and removes the remaining
//   non-structural overhead:
//     - enc+dec phases in ONE kernel: no inter-kernel gap, h handoff in
//       REGISTERS (hold + noise, exact fp32; h_enc global buffer gone),
//       single instantiation (no template-pair regalloc perturbation).
//     - X_f staged upfront into a 2nd LDS x-buffer (LDS 147.7KB <= 160).
//     - decoder Y stores nontemporal (keep L2 clean for wr stream).
// Frozen (R17): 32 blocks x 1024 thr (16 waves, 1 tile/wave, 4/SIMD),
// NBATCH=16 real batches; gate-r k=0..3 LDS frags + k=4..7 global
// prefetch (prep_wr); z,n A-frags resident (64 AGPR); full-width h
// fragment layout, one barrier/step; bias-column x MFMA (q==0 lanes);
// native v_exp gates; interleaved epilogue -> x-step MFMA re-init;
// incremental Y pointers; fp32 register h carry.

#define B_TOT 512
#define T_LEN 256
#define HID 256
#define NBATCH 16
#define NTHREADS 1024
#define NBLK 32

#define XT 64
#define XSLOTS (T_LEN + 1)
#define HBUF (NBATCH * HID)

// LDS partition (units: shorts)
#define WR_OFF 0               // gate-r k=0..3 frags: 16*4*64*8 = 32768
#define H_OFF  32768           // 2 x 4096
#define X1_OFF 40960           // enc x: 257 x 64 = 16448
#define X2_OFF 57408           // dec x: 257 x 64 = 16448
#define SMEM_SHORTS (X2_OFF + XSLOTS * XT)   // 73856
#define SMEM_BYTES  (SMEM_SHORTS * 2)        // 147712 B <= 160 KiB

typedef __attribute__((ext_vector_type(4))) float f32x4;
typedef __attribute__((ext_vector_type(8))) short shortx8;
typedef __attribute__((ext_vector_type(4))) short i16x4;
typedef __attribute__((ext_vector_type(4))) unsigned short ushortx4;
typedef __attribute__((ext_vector_type(8))) unsigned short ushortx8;

#if __has_builtin(__builtin_amdgcn_mfma_f32_16x16x16_bf16)
#define HAVE_K16 1
#define MFMA_X(A, B, C) __builtin_amdgcn_mfma_f32_16x16x16_bf16((A), (B), (C), 0, 0, 0)
#elif __has_builtin(__builtin_amdgcn_mfma_f32_16x16x16bf16_1k)
#define HAVE_K16 1
#define MFMA_X(A, B, C) __builtin_amdgcn_mfma_f32_16x16x16bf16_1k((A), (B), (C), 0, 0, 0)
#else
#define HAVE_K16 0
#endif

__device__ __forceinline__ unsigned short f2bf(float x) {
    unsigned u = __float_as_uint(x);
    u += 0x7FFF + ((u >> 16) & 1);   // RNE
    return (unsigned short)(u >> 16);
}
__device__ __forceinline__ float bf2f(unsigned short s) {
    return __uint_as_float(((unsigned)s) << 16);
}
__device__ __forceinline__ float fastrcp(float x) {
#if __has_builtin(__builtin_amdgcn_rcpf)
    return __builtin_amdgcn_rcpf(x);
#else
    return 1.0f / x;
#endif
}
__device__ __forceinline__ float exp2raw(float y) {
#if __has_builtin(__builtin_amdgcn_exp2f)
    return __builtin_amdgcn_exp2f(y);
#else
    return __expf(y * 0.69314718056f);
#endif
}
__device__ __forceinline__ float sigmoid_(float x) {
    return fastrcp(1.0f + exp2raw(x * -1.44269504f));
}
__device__ __forceinline__ float tanh_(float x) {
    return 2.0f * fastrcp(1.0f + exp2raw(x * -2.88539008f)) - 1.0f;
}

// Pack gate-r (rows 0..255 of W_hh), K-half k=4..7, into per-lane fragment
// layout: dst[((ht*4+kk)*64+lane)*8+j] = bf16(W[ht*16+(lane&15)][(kk+4)*32+(lane>>4)*8+j])
__global__ __launch_bounds__(256) void prep_wr(
    const float* __restrict__ Whh_enc, const float* __restrict__ Whh_dec,
    unsigned short* __restrict__ wr_enc, unsigned short* __restrict__ wr_dec)
{
    int idx = blockIdx.x * 256 + threadIdx.x;    // 0..8191
    int gru = idx >> 12;
    int rem = idx & 4095;                        // (ht*4+kk)*64 + lane
    int lane = rem & 63;
    int kk = (rem >> 6) & 3;
    int ht = rem >> 8;
    const float* W = gru ? Whh_dec : Whh_enc;
    unsigned short* dst = gru ? wr_dec : wr_enc;
    int row = ht * 16 + (lane & 15);
    int col = (kk + 4) * 32 + (lane >> 4) * 8;
    const float* src = W + (size_t)row * 256 + col;
    ushortx8 v;
    #pragma unroll
    for (int j = 0; j < 8; ++j) v[j] = f2bf(src[j]);
    *(ushortx8*)(dst + (size_t)rem * 8) = v;
}

__global__ __launch_bounds__(NTHREADS, 1) void gru_fused(
    const float* __restrict__ X_p,     // [512][256][3]
    const float* __restrict__ X_f,     // [512][256][3]
    const float* __restrict__ Whh_e,   // [768][256] gates r,z,n
    const float* __restrict__ Whh_d,
    const float* __restrict__ Wih_e,   // [768][3]
    const float* __restrict__ Wih_d,
    const float* __restrict__ bih_e,   // [768]
    const float* __restrict__ bih_d,
    const float* __restrict__ bhh_e,   // [768]
    const float* __restrict__ bhh_d,
    const unsigned short* __restrict__ wr_e, // gate-r k=4..7 frags
    const unsigned short* __restrict__ wr_d,
    const float* __restrict__ noise,   // [512][256]
    unsigned short* __restrict__ Yout) // [32][256][16][256] bf16
{
    extern __shared__ unsigned short smem[];
    unsigned short* shWr = smem + WR_OFF;
    unsigned short* shH  = smem + H_OFF;

    const int tid  = threadIdx.x;
    const int g    = blockIdx.x;
    const int w    = tid >> 6;        // wave 0..15; owns hidden tile ht = w
    const int lane = tid & 63;
    const int c    = lane & 15;
    const int q    = lane >> 4;
    const int ht   = w;

    // ---- stage BOTH x sequences into LDS (dec shift baked into X2) ----
    for (int idx = tid; idx < NBATCH * XSLOTS * 2; idx += NTHREADS) {
        int half = idx >= NBATCH * XSLOTS;
        int rem = half ? idx - NBATCH * XSLOTS : idx;
        int t = rem >> 4, cc = rem & 15;
        int ts = half ? (t - 1) : t;
        const float* Xsrc = half ? X_f : X_p;
        float x0 = 0.0f, x1 = 0.0f, x2 = 0.0f;
        if (ts >= 0 && ts < T_LEN) {
            const float* xp = Xsrc + ((size_t)(g * NBATCH + cc) * T_LEN + ts) * 3;
            x0 = xp[0]; x1 = xp[1]; x2 = xp[2];
        }
        ushortx4 v = {f2bf(x0), f2bf(x1), f2bf(x2), (unsigned short)0x3F80};
        *(ushortx4*)&smem[(half ? X2_OFF : X1_OFF) + t * XT + cc * 4] = v;
    }

    // ---- loop-invariant lane constants ----
    int woff;
    {
        int kk = ht >> 1;
        int qq = ((ht & 1) << 1) | (q >> 1);
        woff = ((kk * 4 + qq) * 16 + c) * 8 + (q & 1) * 4;
    }
    const int bbase = q * 128 + c * 8;
    const unsigned short* ab = shWr + ((size_t)(ht * 4) * 64 + lane) * 8;
    const f32x4 zc = {0.0f, 0.0f, 0.0f, 0.0f};

    float hold0 = 0.0f, hold1 = 0.0f, hold2 = 0.0f, hold3 = 0.0f;

    for (int phase = 0; phase < 2; ++phase) {
        const float* W_hh = phase ? Whh_d : Whh_e;
        const float* W_ih = phase ? Wih_d : Wih_e;
        const float* b_ih = phase ? bih_d : bih_e;
        const float* b_hh = phase ? bhh_d : bhh_e;
        const unsigned short* Wr4 = phase ? wr_d : wr_e;
        const unsigned short* shX = smem + (phase ? X2_OFF : X1_OFF);

        __syncthreads();   // phase 1: prior-phase reads done before restage

        // ---- gate-r k=0..3 frags -> LDS (each wave stages its tile) ----
        {
            int row = ht * 16 + c;                      // gate r
            const float* wp = W_hh + (size_t)row * 256 + q * 8;
            #pragma unroll
            for (int k = 0; k < 4; ++k) {
                const f32x4* p = (const f32x4*)(wp + k * 32);
                f32x4 f0 = p[0];
                f32x4 f1 = p[1];
                shortx8 a;
                a[0] = (short)f2bf(f0[0]); a[1] = (short)f2bf(f0[1]);
                a[2] = (short)f2bf(f0[2]); a[3] = (short)f2bf(f0[3]);
                a[4] = (short)f2bf(f1[0]); a[5] = (short)f2bf(f1[1]);
                a[6] = (short)f2bf(f1[2]); a[7] = (short)f2bf(f1[3]);
                *(shortx8*)&shWr[((ht * 4 + k) * 64 + lane) * 8] = a;
            }
        }

        // ---- gates z,n A-frags resident (64 regs) ----
        shortx8 Wf[2][8];   // [z|n][k]
        #pragma unroll
        for (int gg = 0; gg < 2; ++gg) {
            int row = (gg + 1) * 256 + ht * 16 + c;
            const float* wp = W_hh + (size_t)row * 256 + q * 8;
            #pragma unroll
            for (int k = 0; k < 8; ++k) {
                const f32x4* p = (const f32x4*)(wp + k * 32);
                f32x4 f0 = p[0];
                f32x4 f1 = p[1];
                shortx8 a;
                a[0] = (short)f2bf(f0[0]); a[1] = (short)f2bf(f0[1]);
                a[2] = (short)f2bf(f0[2]); a[3] = (short)f2bf(f0[3]);
                a[4] = (short)f2bf(f1[0]); a[5] = (short)f2bf(f1[1]);
                a[6] = (short)f2bf(f1[2]); a[7] = (short)f2bf(f1[3]);
                Wf[gg][k] = a;
            }
        }

        // ---- x/bias A-frags (q==0 lanes carry data; others zero) ----
#if HAVE_K16
        i16x4 ax[3];
#else
        shortx8 ax[3];
#endif
        {
            int rr_ = ht * 16 + c;
            int rowr = rr_, rowz = 256 + rr_, rown = 512 + rr_;
            short r0 = 0, r1 = 0, r2 = 0, r3 = 0, z0 = 0, z1 = 0, z2 = 0, z3 = 0;
            short n0 = 0, n1 = 0, n2 = 0, n3 = 0;
            if (q == 0) {
                r0 = (short)f2bf(W_ih[rowr * 3 + 0]);
                r1 = (short)f2bf(W_ih[rowr * 3 + 1]);
                r2 = (short)f2bf(W_ih[rowr * 3 + 2]);
                r3 = (short)f2bf(b_ih[rowr] + b_hh[rowr]);
                z0 = (short)f2bf(W_ih[rowz * 3 + 0]);
                z1 = (short)f2bf(W_ih[rowz * 3 + 1]);
                z2 = (short)f2bf(W_ih[rowz * 3 + 2]);
                z3 = (short)f2bf(b_ih[rowz] + b_hh[rowz]);
                n0 = (short)f2bf(W_ih[rown * 3 + 0]);
                n1 = (short)f2bf(W_ih[rown * 3 + 1]);
                n2 = (short)f2bf(W_ih[rown * 3 + 2]);
                n3 = (short)f2bf(b_ih[rown]);
            }
#if HAVE_K16
            ax[0] = i16x4{r0, r1, r2, r3};
            ax[1] = i16x4{z0, z1, z2, z3};
            ax[2] = i16x4{n0, n1, n2, n3};
#else
            ax[0] = shortx8{r0, r1, r2, r3, 0, 0, 0, 0};
            ax[1] = shortx8{z0, z1, z2, z3, 0, 0, 0, 0};
            ax[2] = shortx8{n0, n1, n2, n3, 0, 0, 0, 0};
#endif
        }

        // ---- nh-bias register constants ----
        f32x4 nhb = *(const f32x4*)(b_hh + 512 + ht * 16 + q * 4);

        // ---- phase h0: enc = 0; dec = enc-final (regs, exact) + noise ----
        if (phase == 0) {
            hold0 = hold1 = hold2 = hold3 = 0.0f;
        } else {
            int b = g * NBATCH + c;
            int dim0 = ht * 16 + q * 4;
            f32x4 nz = *(const f32x4*)(noise + (size_t)b * HID + dim0);
            hold0 += nz[0]; hold1 += nz[1]; hold2 += nz[2]; hold3 += nz[3];
        }
        {
            ushortx4 hb16 = {f2bf(hold0), f2bf(hold1), f2bf(hold2), f2bf(hold3)};
            *(ushortx4*)&shH[woff] = hb16;   // parity buffer 0
        }

        // ---- incremental decoder Y pointer (phase 1 only) ----
        unsigned short* yp = Yout + ((size_t)g * T_LEN * NBATCH + c) * HID
                           + ht * 16 + q * 4;

        const unsigned short* gb = Wr4 + ((size_t)(ht * 4) * 64 + lane) * 8;

        __syncthreads();

        // ---- x-step for t=0 ----
        f32x4 acc0, acc1, acc2, acc3;   // r, z, nh, nx
        {
#if HAVE_K16
            i16x4 bx = *(const i16x4*)&shX[c * 4];
            acc0 = MFMA_X(ax[0], bx, zc);
            acc1 = MFMA_X(ax[1], bx, zc);
            acc3 = MFMA_X(ax[2], bx, zc);
#else
            ushortx4 xv = *(const ushortx4*)&shX[c * 4];
            shortx8 bx = (q == 0)
                ? shortx8{(short)xv[0], (short)xv[1], (short)xv[2], (short)xv[3], 0, 0, 0, 0}
                : shortx8{0, 0, 0, 0, 0, 0, 0, 0};
            acc0 = __builtin_amdgcn_mfma_f32_16x16x32_bf16(ax[0], bx, zc, 0, 0, 0);
            acc1 = __builtin_amdgcn_mfma_f32_16x16x32_bf16(ax[1], bx, zc, 0, 0, 0);
            acc3 = __builtin_amdgcn_mfma_f32_16x16x32_bf16(ax[2], bx, zc, 0, 0, 0);
#endif
        }

        int xidx = XT + c * 4;   // x slot for step t+1 (incremental)

        // ---- recurrence (R17 body, verbatim) ----
        for (int t = 0; t < T_LEN; ++t) {
            const unsigned short* brow = shH + (t & 1) * HBUF + bbase;
            unsigned short* hn = shH + ((t + 1) & 1) * HBUF;

            // gate-r k=4..7 from global: issued at step start, consumed
            // after the LDS half (proven prefetch timing)
            shortx8 gr[4];
            #pragma unroll
            for (int kk = 0; kk < 4; ++kk)
                gr[kk] = *(const shortx8*)(gb + kk * 512);

            acc2 = nhb;

            // k=0..3: gate-r from LDS
            #pragma unroll
            for (int k = 0; k < 4; ++k) {
                shortx8 bf = *(const shortx8*)(brow + k * 512);
                shortx8 ar = *(const shortx8*)(ab + k * 512);
                acc0 = __builtin_amdgcn_mfma_f32_16x16x32_bf16(ar,       bf, acc0, 0, 0, 0);
                acc1 = __builtin_amdgcn_mfma_f32_16x16x32_bf16(Wf[0][k], bf, acc1, 0, 0, 0);
                acc2 = __builtin_amdgcn_mfma_f32_16x16x32_bf16(Wf[1][k], bf, acc2, 0, 0, 0);
            }
            // k=4..7: gate-r from the global prefetch
            #pragma unroll
            for (int k = 4; k < 8; ++k) {
                shortx8 bf = *(const shortx8*)(brow + k * 512);
                acc0 = __builtin_amdgcn_mfma_f32_16x16x32_bf16(gr[k - 4], bf, acc0, 0, 0, 0);
                acc1 = __builtin_amdgcn_mfma_f32_16x16x32_bf16(Wf[0][k],  bf, acc1, 0, 0, 0);
                acc2 = __builtin_amdgcn_mfma_f32_16x16x32_bf16(Wf[1][k],  bf, acc2, 0, 0, 0);
            }

            // bx for step t+1
#if HAVE_K16
            i16x4 bxn = *(const i16x4*)&shX[xidx];
#else
            ushortx4 xvn = *(const ushortx4*)&shX[xidx];
            shortx8 bxn = (q == 0)
                ? shortx8{(short)xvn[0], (short)xvn[1], (short)xvn[2], (short)xvn[3], 0, 0, 0, 0}
                : shortx8{0, 0, 0, 0, 0, 0, 0, 0};
#endif
            xidx += XT;

            // ---- epilogue (4 values) ----
            {
                float rr, zz, nn;
                rr = sigmoid_(acc0[0]); zz = sigmoid_(acc1[0]);
                nn = tanh_(acc3[0] + rr * acc2[0]);
                hold0 = nn + zz * (hold0 - nn);
                rr = sigmoid_(acc0[1]); zz = sigmoid_(acc1[1]);
                nn = tanh_(acc3[1] + rr * acc2[1]);
                hold1 = nn + zz * (hold1 - nn);
                rr = sigmoid_(acc0[2]); zz = sigmoid_(acc1[2]);
                nn = tanh_(acc3[2] + rr * acc2[2]);
                hold2 = nn + zz * (hold2 - nn);
                rr = sigmoid_(acc0[3]); zz = sigmoid_(acc1[3]);
                nn = tanh_(acc3[3] + rr * acc2[3]);
                hold3 = nn + zz * (hold3 - nn);
                ushortx4 hb16 = {f2bf(hold0), f2bf(hold1), f2bf(hold2), f2bf(hold3)};
                *(ushortx4*)(hn + woff) = hb16;
                if (phase) {
                    __builtin_nontemporal_store(hb16, (ushortx4*)yp);
                    yp += NBATCH * HID;   // stride 4096 shorts per step
                }
            }

            // x-step re-init for t+1 (independent MFMAs under trans tail)
#if HAVE_K16
            acc0 = MFMA_X(ax[0], bxn, zc);
            acc1 = MFMA_X(ax[1], bxn, zc);
            acc3 = MFMA_X(ax[2], bxn, zc);
#else
            acc0 = __builtin_amdgcn_mfma_f32_16x16x32_bf16(ax[0], bxn, zc, 0, 0, 0);
            acc1 = __builtin_amdgcn_mfma_f32_16x16x32_bf16(ax[1], bxn, zc, 0, 0, 0);
            acc3 = __builtin_amdgcn_mfma_f32_16x16x32_bf16(ax[2], bxn, zc, 0, 0, 0);
#endif
            __syncthreads();
        }
    }
}

// out[b][t][d] = sum_h Y[g][t][b16][h] * W_fc[d][h] + b_fc[d]
__global__ __launch_bounds__(256) void proj_kernel(
    const unsigned short* __restrict__ Y, const float* __restrict__ W_fc,
    const float* __restrict__ b_fc, float* __restrict__ out)
{
    int row = blockIdx.x * 256 + threadIdx.x;  // ((g*T + t)*16 + b16)
    int b16 = row & 15;
    int gt = row >> 4;
    int t = gt & (T_LEN - 1);
    int g = gt >> 8;
    const unsigned short* y = Y + (size_t)row * HID;
    float a0 = b_fc[0], a1 = b_fc[1], a2 = b_fc[2];
    #pragma unroll 4
    for (int k8 = 0; k8 < 32; ++k8) {
        ushortx8 v = *(const ushortx8*)(y + k8 * 8);
        #pragma unroll
        for (int j = 0; j < 8; ++j) {
            float f = bf2f(v[j]);
            int k = k8 * 8 + j;
            a0 += f * W_fc[k];          // uniform -> scalar loads
            a1 += f * W_fc[256 + k];
            a2 += f * W_fc[512 + k];
        }
    }
    int batch = g * NBATCH + b16;
    float* o = out + ((size_t)batch * T_LEN + t) * 3;
    o[0] = a0; o[1] = a1; o[2] = a2;
}

extern "C" void kernel_launch(void* const* d_in, const int* in_sizes, int n_in,
                              void* d_out, int out_size, void* d_ws, size_t ws_size,
                              hipStream_t stream)
{
    const float* X_p      = (const float*)d_in[0];
    const float* X_f      = (const float*)d_in[1];
    const float* noise    = (const float*)d_in[2];
    const float* W_ih_enc = (const float*)d_in[3];
    const float* W_hh_enc = (const float*)d_in[4];
    const float* b_ih_enc = (const float*)d_in[5];
    const float* b_hh_enc = (const float*)d_in[6];
    const float* W_ih_dec = (const float*)d_in[7];
    const float* W_hh_dec = (const float*)d_in[8];
    const float* b_ih_dec = (const float*)d_in[9];
    const float* b_hh_dec = (const float*)d_in[10];
    const float* W_fc     = (const float*)d_in[11];
    const float* b_fc     = (const float*)d_in[12];

    // allow >64 KiB dynamic LDS (idempotent; host-side, graph-capture safe)
    (void)hipFuncSetAttribute((const void*)&gru_fused,
                              hipFuncAttributeMaxDynamicSharedMemorySize, SMEM_BYTES);

    // ws: [0,64K) Wr_enc | [64K,128K) Wr_dec | [128K, +67.1MB) dec Y bf16
    unsigned short* wr_enc = (unsigned short*)d_ws;
    unsigned short* wr_dec = (unsigned short*)((char*)d_ws + (64u << 10));
    unsigned short* Yws    = (unsigned short*)((char*)d_ws + (128u << 10));

    hipLaunchKernelGGL(prep_wr, dim3(32), dim3(256), 0, stream,
        W_hh_enc, W_hh_dec, wr_enc, wr_dec);

    hipLaunchKernelGGL(gru_fused, dim3(NBLK), dim3(NTHREADS), SMEM_BYTES, stream,
        X_p, X_f, W_hh_enc, W_hh_dec, W_ih_enc, W_ih_dec,
        b_ih_enc, b_ih_dec, b_hh_enc, b_hh_dec,
        wr_enc, wr_dec, noise, Yws);

    hipLaunchKernelGGL(proj_kernel, dim3((B_TOT * T_LEN) / 256), dim3(256), 0, stream,
        Yws, W_fc, b_fc, (float*)d_out);
}